// Round 2
// baseline (105.038 us; speedup 1.0000x reference)
//
#include <hip/hip_runtime.h>
#include <math.h>

// Problem constants (match reference)
#define NTOT 8192
#define THRESH 0.5f
#define EPS_F 1e-8f

// Workspace float layout
#define OFF_BCE 0
#define OFF_CNT 1              // stored as unsigned int
#define OFF_TXY 2
#define OFF_TXX 3
#define OFF_TYY 4
#define OFF_ROWX 8
#define OFF_ROWY (OFF_ROWX + NTOT)
#define OFF_PS   (OFF_ROWY + NTOT)
#define OFF_SS   (OFF_PS + NTOT)
#define ZERO_FLOATS OFF_PS     // zero [0, OFF_PS): scalars + rowx + rowy

#define JCHUNK 1024
#define IBLOCKS (NTOT / 256)   // 32
#define NJ (NTOT / JCHUNK)     // 8

__device__ inline float wave_reduce(float v) {
#pragma unroll
    for (int o = 32; o > 0; o >>= 1) v += __shfl_down(v, o, 64);
    return v;
}

// Pass 1: BCE partial sum + sigmoid + mask compaction.
__global__ void k_stage1(const float* __restrict__ x, const float* __restrict__ t,
                         const float* __restrict__ s, float* __restrict__ ws) {
    int i = blockIdx.x * blockDim.x + threadIdx.x;
    float bce = 0.f;
    if (i < NTOT) {
        float xi = x[i], ti = t[i], si = s[i];
        bce = fmaxf(xi, 0.f) - xi * ti + log1pf(expf(-fabsf(xi)));
        if (si >= THRESH) {
            unsigned pos = atomicAdd((unsigned*)(ws + OFF_CNT), 1u);
            float p = 1.f / (1.f + expf(-xi));
            ws[OFF_PS + pos] = p;
            ws[OFF_SS + pos] = si;
        }
    }
    bce = wave_reduce(bce);
    if ((threadIdx.x & 63) == 0) atomicAdd(ws + OFF_BCE, bce);
}

// Pass 2: all-pairs over the compacted set.
// Each block: one i-chunk of 256 rows x one j-chunk of JCHUNK cols (LDS-staged).
__global__ void k_pairs(float* __restrict__ ws) {
    __shared__ float pj[JCHUNK];
    __shared__ float sj[JCHUNK];
    int c = (int)*((unsigned*)(ws + OFF_CNT));
    int ib = blockIdx.x & (IBLOCKS - 1);
    int jb = blockIdx.x / IBLOCKS;
    int j0 = jb * JCHUNK;
    if (j0 >= c) return;                      // uniform per block: safe
    int nj = min(JCHUNK, c - j0);
    for (int j = threadIdx.x; j < nj; j += blockDim.x) {
        pj[j] = ws[OFF_PS + j0 + j];
        sj[j] = ws[OFF_SS + j0 + j];
    }
    __syncthreads();

    float t_xy = 0.f, t_xx = 0.f, t_yy = 0.f;
    int i = ib * blockDim.x + threadIdx.x;
    if (i < c) {
        float pi = ws[OFF_PS + i], si = ws[OFF_SS + i];
        float rsx = 0.f, rsy = 0.f;
#pragma unroll 4
        for (int j = 0; j < nj; ++j) {
            float dx = fabsf(pi - pj[j]);     // LDS broadcast read
            float dy = fabsf(si - sj[j]);
            rsx += dx;
            rsy += dy;
            t_xy = fmaf(dx, dy, t_xy);
            t_xx = fmaf(dx, dx, t_xx);
            t_yy = fmaf(dy, dy, t_yy);
        }
        atomicAdd(ws + OFF_ROWX + i, rsx);
        atomicAdd(ws + OFF_ROWY + i, rsy);
    }
    t_xy = wave_reduce(t_xy);
    t_xx = wave_reduce(t_xx);
    t_yy = wave_reduce(t_yy);
    if ((threadIdx.x & 63) == 0) {
        atomicAdd(ws + OFF_TXY, t_xy);
        atomicAdd(ws + OFF_TXX, t_xx);
        atomicAdd(ws + OFF_TYY, t_yy);
    }
}

// Pass 3: reduce row sums, assemble dCor + BCE.
__global__ void k_final(const float* __restrict__ ws, float* __restrict__ out) {
    __shared__ float acc[5];
    int c = (int)*((const unsigned*)(ws + OFF_CNT));
    if (threadIdx.x < 5) acc[threadIdx.x] = 0.f;
    __syncthreads();
    float sx = 0, sy = 0, sxy = 0, sxx = 0, syy = 0;
    for (int i = threadIdx.x; i < c; i += blockDim.x) {
        float rx = ws[OFF_ROWX + i], ry = ws[OFF_ROWY + i];
        sx += rx;
        sy += ry;
        sxy = fmaf(rx, ry, sxy);
        sxx = fmaf(rx, rx, sxx);
        syy = fmaf(ry, ry, syy);
    }
    sx = wave_reduce(sx);
    sy = wave_reduce(sy);
    sxy = wave_reduce(sxy);
    sxx = wave_reduce(sxx);
    syy = wave_reduce(syy);
    if ((threadIdx.x & 63) == 0) {
        atomicAdd(&acc[0], sx);
        atomicAdd(&acc[1], sy);
        atomicAdd(&acc[2], sxy);
        atomicAdd(&acc[3], sxx);
        atomicAdd(&acc[4], syy);
    }
    __syncthreads();
    if (threadIdx.x == 0) {
        float bce = ws[OFF_BCE] / (float)NTOT;
        float cf = fmaxf((float)c, 1.f);
        float ic2 = 1.f / (cf * cf);
        float ic3 = ic2 / cf;
        float ic4 = ic2 * ic2;
        // masked mean-products via the dCov expansion identity
        float Vxy = ws[OFF_TXY] * ic2 - 2.f * acc[2] * ic3 + acc[0] * acc[1] * ic4;
        float Vxx = ws[OFF_TXX] * ic2 - 2.f * acc[3] * ic3 + acc[0] * acc[0] * ic4;
        float Vyy = ws[OFF_TYY] * ic2 - 2.f * acc[4] * ic3 + acc[1] * acc[1] * ic4;
        float dcor = sqrtf(fmaxf(Vxy, EPS_F)) /
                     (sqrtf(fmaxf(Vxx, EPS_F)) * sqrtf(fmaxf(Vyy, EPS_F)));
        out[0] = bce + (c > 0 ? dcor : 0.f);
    }
}

extern "C" void kernel_launch(void* const* d_in, const int* in_sizes, int n_in,
                              void* d_out, int out_size, void* d_ws, size_t ws_size,
                              hipStream_t stream) {
    const float* x = (const float*)d_in[0];   // inputs  [8192]
    const float* t = (const float*)d_in[1];   // targets [8192]
    const float* s = (const float*)d_in[2];   // spectators [8192]
    float* ws = (float*)d_ws;
    float* out = (float*)d_out;

    hipMemsetAsync(d_ws, 0, ZERO_FLOATS * sizeof(float), stream);
    k_stage1<<<NTOT / 256, 256, 0, stream>>>(x, t, s, ws);
    k_pairs<<<IBLOCKS * NJ, 256, 0, stream>>>(ws);
    k_final<<<1, 256, 0, stream>>>(ws, out);
}

// Round 3
// 93.806 us; speedup vs baseline: 1.1197x; 1.1197x over previous
//
#include <hip/hip_runtime.h>
#include <math.h>

// Problem constants (match reference)
#define NTOT 8192
#define THRESH 0.5f
#define EPS_F 1e-8f

// Workspace float layout
#define OFF_BCE 0
#define OFF_CNT 1              // stored as unsigned int
#define OFF_TXY 2
#define OFF_TXX 3
#define OFF_TYY 4
#define OFF_ROWX 8
#define OFF_ROWY (OFF_ROWX + NTOT)
#define OFF_PS   (OFF_ROWY + NTOT)
#define OFF_SS   (OFF_PS + NTOT)
#define ZERO_FLOATS OFF_PS     // zero [0, OFF_PS): scalars + rowx + rowy

// Pairs tiling: 256-row i-tiles x 128-col j-tiles for occupancy.
#define IT 256
#define JT 128
#define I_TILES (NTOT / IT)    // 32
#define J_TILES (NTOT / JT)    // 64

__device__ inline float wave_reduce(float v) {
#pragma unroll
    for (int o = 32; o > 0; o >>= 1) v += __shfl_down(v, o, 64);
    return v;
}

// Pass 1: BCE partial sum + sigmoid + mask compaction.
__global__ void k_stage1(const float* __restrict__ x, const float* __restrict__ t,
                         const float* __restrict__ s, float* __restrict__ ws) {
    int i = blockIdx.x * blockDim.x + threadIdx.x;
    float bce = 0.f;
    if (i < NTOT) {
        float xi = x[i], ti = t[i], si = s[i];
        bce = fmaxf(xi, 0.f) - xi * ti + log1pf(expf(-fabsf(xi)));
        if (si >= THRESH) {
            unsigned pos = atomicAdd((unsigned*)(ws + OFF_CNT), 1u);
            float p = 1.f / (1.f + expf(-xi));
            ws[OFF_PS + pos] = p;
            ws[OFF_SS + pos] = si;
        }
    }
    bce = wave_reduce(bce);
    if ((threadIdx.x & 63) == 0) atomicAdd(ws + OFF_BCE, bce);
}

// Pass 2: all-pairs over the compacted set.
// Block = (i-tile of 256 rows) x (j-tile of 128 cols, LDS-staged).
// Grid sized for worst case c = NTOT; inactive tiles exit immediately.
__global__ void k_pairs(float* __restrict__ ws) {
    __shared__ float pj[JT];
    __shared__ float sj[JT];
    __shared__ float acc3[3];
    int c = (int)*((unsigned*)(ws + OFF_CNT));
    int ib = blockIdx.x & (I_TILES - 1);
    int jb = blockIdx.x / I_TILES;
    int i0 = ib * IT;
    int j0 = jb * JT;
    if (i0 >= c || j0 >= c) return;           // uniform per block: safe
    int nj = min(JT, c - j0);
    int tid = threadIdx.x;
    if (tid < nj) {
        pj[tid] = ws[OFF_PS + j0 + tid];
        sj[tid] = ws[OFF_SS + j0 + tid];
    }
    if (tid < 3) acc3[tid] = 0.f;
    __syncthreads();

    float t_xy = 0.f, t_xx = 0.f, t_yy = 0.f;
    int i = i0 + tid;
    if (i < c) {
        float pi = ws[OFF_PS + i], si = ws[OFF_SS + i];
        float rsx = 0.f, rsy = 0.f;
#pragma unroll 8
        for (int j = 0; j < nj; ++j) {
            float d1 = pi - pj[j];            // LDS broadcast read
            float d2 = si - sj[j];
            float a1 = fabsf(d1);             // folds to abs-modifier on consumers
            float a2 = fabsf(d2);
            rsx += a1;
            rsy += a2;
            t_xy = fmaf(a1, a2, t_xy);
            t_xx = fmaf(d1, d1, t_xx);        // |d|^2 == d^2: no abs needed
            t_yy = fmaf(d2, d2, t_yy);
        }
        atomicAdd(ws + OFF_ROWX + i, rsx);
        atomicAdd(ws + OFF_ROWY + i, rsy);
    }
    t_xy = wave_reduce(t_xy);
    t_xx = wave_reduce(t_xx);
    t_yy = wave_reduce(t_yy);
    if ((tid & 63) == 0) {                    // per-wave -> LDS
        atomicAdd(&acc3[0], t_xy);
        atomicAdd(&acc3[1], t_xx);
        atomicAdd(&acc3[2], t_yy);
    }
    __syncthreads();
    if (tid == 0) {                           // one global atomic triple per block
        atomicAdd(ws + OFF_TXY, acc3[0]);
        atomicAdd(ws + OFF_TXX, acc3[1]);
        atomicAdd(ws + OFF_TYY, acc3[2]);
    }
}

// Pass 3: reduce row sums, assemble dCor + BCE.
__global__ void k_final(const float* __restrict__ ws, float* __restrict__ out) {
    __shared__ float acc[5];
    int c = (int)*((const unsigned*)(ws + OFF_CNT));
    if (threadIdx.x < 5) acc[threadIdx.x] = 0.f;
    __syncthreads();
    float sx = 0, sy = 0, sxy = 0, sxx = 0, syy = 0;
    for (int i = threadIdx.x; i < c; i += blockDim.x) {
        float rx = ws[OFF_ROWX + i], ry = ws[OFF_ROWY + i];
        sx += rx;
        sy += ry;
        sxy = fmaf(rx, ry, sxy);
        sxx = fmaf(rx, rx, sxx);
        syy = fmaf(ry, ry, syy);
    }
    sx = wave_reduce(sx);
    sy = wave_reduce(sy);
    sxy = wave_reduce(sxy);
    sxx = wave_reduce(sxx);
    syy = wave_reduce(syy);
    if ((threadIdx.x & 63) == 0) {
        atomicAdd(&acc[0], sx);
        atomicAdd(&acc[1], sy);
        atomicAdd(&acc[2], sxy);
        atomicAdd(&acc[3], sxx);
        atomicAdd(&acc[4], syy);
    }
    __syncthreads();
    if (threadIdx.x == 0) {
        float bce = ws[OFF_BCE] / (float)NTOT;
        float cf = fmaxf((float)c, 1.f);
        float ic2 = 1.f / (cf * cf);
        float ic3 = ic2 / cf;
        float ic4 = ic2 * ic2;
        // masked mean-products via the dCov expansion identity
        float Vxy = ws[OFF_TXY] * ic2 - 2.f * acc[2] * ic3 + acc[0] * acc[1] * ic4;
        float Vxx = ws[OFF_TXX] * ic2 - 2.f * acc[3] * ic3 + acc[0] * acc[0] * ic4;
        float Vyy = ws[OFF_TYY] * ic2 - 2.f * acc[4] * ic3 + acc[1] * acc[1] * ic4;
        float dcor = sqrtf(fmaxf(Vxy, EPS_F)) /
                     (sqrtf(fmaxf(Vxx, EPS_F)) * sqrtf(fmaxf(Vyy, EPS_F)));
        out[0] = bce + (c > 0 ? dcor : 0.f);
    }
}

extern "C" void kernel_launch(void* const* d_in, const int* in_sizes, int n_in,
                              void* d_out, int out_size, void* d_ws, size_t ws_size,
                              hipStream_t stream) {
    const float* x = (const float*)d_in[0];   // inputs  [8192]
    const float* t = (const float*)d_in[1];   // targets [8192]
    const float* s = (const float*)d_in[2];   // spectators [8192]
    float* ws = (float*)d_ws;
    float* out = (float*)d_out;

    hipMemsetAsync(d_ws, 0, ZERO_FLOATS * sizeof(float), stream);
    k_stage1<<<NTOT / 256, 256, 0, stream>>>(x, t, s, ws);
    k_pairs<<<I_TILES * J_TILES, 256, 0, stream>>>(ws);
    k_final<<<1, 256, 0, stream>>>(ws, out);
}